// Round 4
// baseline (231.963 us; speedup 1.0000x reference)
//
#include <hip/hip_runtime.h>
#include <hip/hip_bf16.h>
#include <stdint.h>

typedef _Float16 f16;
typedef _Float16 f16x8 __attribute__((ext_vector_type(8)));
typedef float f32x4 __attribute__((ext_vector_type(4)));

#define AS1 __attribute__((address_space(1)))
#define AS3 __attribute__((address_space(3)))

// ---------------------------------------------------------------------------
// Transpose + fp32->fp16 convert:  src [R][C] f32  ->  dst [C][R] f16
// ---------------------------------------------------------------------------
__global__ __launch_bounds__(256) void tr_cvt_kernel(
    const float* __restrict__ src, f16* __restrict__ dst, int R, int C)
{
    __shared__ float tile[64][65];
    const int b = blockIdx.z;
    src += (size_t)b * R * C;
    dst += (size_t)b * R * C;
    const int c0 = blockIdx.x * 64;
    const int r0 = blockIdx.y * 64;
    const int t = threadIdx.x;
    {
        const int cc = (t & 15) * 4;
        const int rr = t >> 4;
#pragma unroll
        for (int p = 0; p < 4; ++p) {
            const int r = rr + p * 16;
            const float4 v = *(const float4*)(src + (size_t)(r0 + r) * C + c0 + cc);
            tile[r][cc + 0] = v.x; tile[r][cc + 1] = v.y;
            tile[r][cc + 2] = v.z; tile[r][cc + 3] = v.w;
        }
    }
    __syncthreads();
    {
        const int rq = (t & 15) * 4;
        const int cp = t >> 4;
#pragma unroll
        for (int p = 0; p < 4; ++p) {
            const int c = cp + p * 16;
            ushort4 o;
            f16 h0 = (f16)tile[rq + 0][c];
            f16 h1 = (f16)tile[rq + 1][c];
            f16 h2 = (f16)tile[rq + 2][c];
            f16 h3 = (f16)tile[rq + 3][c];
            o.x = __builtin_bit_cast(unsigned short, h0);
            o.y = __builtin_bit_cast(unsigned short, h1);
            o.z = __builtin_bit_cast(unsigned short, h2);
            o.w = __builtin_bit_cast(unsigned short, h3);
            *(ushort4*)(dst + (size_t)(c0 + c) * R + r0 + rq) = o;
        }
    }
}

// ---------------------------------------------------------------------------
// Common 128x128-tile, BK=64 GEMM body: C += A[128,K] * Bt[128,K]^T
// ---------------------------------------------------------------------------
__device__ __forceinline__ void gemm_body(
    const f16* __restrict__ A, const f16* __restrict__ Bt,
    int lda, int ldb, int K, f16* As, f16* Bs,
    f32x4 (&acc)[4][4], int tid)
{
    const int lane = tid & 63, w = tid >> 6;
    const int wr = w >> 1, wc = w & 1;
    const int lrow = lane >> 3;
    const int lcol = (lane & 7) * 8;
    for (int k0 = 0; k0 < K; k0 += 64) {
#pragma unroll
        for (int p = 0; p < 4; ++p) {
            const f16* sa = A + (size_t)(p * 32 + w * 8 + lrow) * lda + k0 + lcol;
            __builtin_amdgcn_global_load_lds(
                (const AS1 uint32_t*)sa,
                (AS3 uint32_t*)((char*)As + p * 4096 + w * 1024), 16, 0, 0);
            const f16* sb = Bt + (size_t)(p * 32 + w * 8 + lrow) * ldb + k0 + lcol;
            __builtin_amdgcn_global_load_lds(
                (const AS1 uint32_t*)sb,
                (AS3 uint32_t*)((char*)Bs + p * 4096 + w * 1024), 16, 0, 0);
        }
        __syncthreads();
#pragma unroll
        for (int kk = 0; kk < 2; ++kk) {
            f16x8 af[4], bfr[4];
#pragma unroll
            for (int i = 0; i < 4; ++i)
                af[i] = *(const f16x8*)&As[(wr * 64 + i * 16 + (lane & 15)) * 64 + kk * 32 + (lane >> 4) * 8];
#pragma unroll
            for (int j = 0; j < 4; ++j)
                bfr[j] = *(const f16x8*)&Bs[(wc * 64 + j * 16 + (lane & 15)) * 64 + kk * 32 + (lane >> 4) * 8];
#pragma unroll
            for (int i = 0; i < 4; ++i)
#pragma unroll
                for (int j = 0; j < 4; ++j)
                    acc[i][j] = __builtin_amdgcn_mfma_f32_16x16x32_f16(af[i], bfr[j], acc[i][j], 0, 0, 0);
        }
        __syncthreads();
    }
}

// ---------------------------------------------------------------------------
// K1: upper-triangle tiles of G_b = xT_b * xT_b^T, split-K=2, f16 partials.
// grid: 576 blocks 1D (36 tiles x 8 batch x 2 splits), XCD-chunked swizzle.
// ---------------------------------------------------------------------------
__global__ __launch_bounds__(256) void gemm_syk(
    const f16* __restrict__ xT, f16* __restrict__ Gp)
{
    __shared__ f16 As[128 * 64];
    __shared__ f16 Bs[128 * 64];
    const int orig = blockIdx.x;
    const int l = (orig & 7) * 72 + (orig >> 3);   // 576 = 8*72, bijective
    const int blk = l % 36;
    const int b = (l / 36) & 7;
    const int s = l / 288;
    int ti = 0, rem = blk;
    while (rem >= 8 - ti) { rem -= 8 - ti; ++ti; }
    const int tj = ti + rem;

    const f16* base = xT + (size_t)b * (1024 * 4096) + (size_t)s * 2048;
    const f16* A  = base + (size_t)ti * 128 * 4096;
    const f16* Bt = base + (size_t)tj * 128 * 4096;

    f32x4 acc[4][4];
#pragma unroll
    for (int i = 0; i < 4; ++i)
#pragma unroll
        for (int j = 0; j < 4; ++j) acc[i][j] = f32x4{0.f, 0.f, 0.f, 0.f};

    gemm_body(A, Bt, 4096, 4096, 2048, As, Bs, acc, threadIdx.x);

    f16* out = Gp + (((size_t)s * 8 + b) * 36 + blk) * 16384;
    const int lane = threadIdx.x & 63, w = threadIdx.x >> 6;
    const int wr = w >> 1, wc = w & 1;
    const int cl = lane & 15, rg = lane >> 4;
#pragma unroll
    for (int i = 0; i < 4; ++i)
#pragma unroll
        for (int j = 0; j < 4; ++j)
#pragma unroll
            for (int q = 0; q < 4; ++q) {
                const int row = wr * 64 + i * 16 + rg * 4 + q;
                const int col = wc * 64 + j * 16 + cl;
                out[row * 128 + col] = (f16)acc[i][j][q];
            }
}

// ---------------------------------------------------------------------------
// Sum 2 split partials -> G tile (f16) + mirrored transpose tile.
// ---------------------------------------------------------------------------
__global__ __launch_bounds__(256) void reduce_mirror(
    const f16* __restrict__ Gp, f16* __restrict__ G)
{
    __shared__ float tile[128][129];
    const int blk = blockIdx.x, b = blockIdx.y;
    int ti = 0, rem = blk;
    while (rem >= 8 - ti) { rem -= 8 - ti; ++ti; }
    const int tj = ti + rem;
    const size_t tb = ((size_t)b * 36 + blk) * 16384;
    const size_t sstride = (size_t)8 * 36 * 16384;
    f16* Gb = G + (size_t)b * (1024 * 1024);
    const int t = threadIdx.x;

#pragma unroll
    for (int i = 0; i < 8; ++i) {
        const int e = (i * 256 + t) * 8;
        const int r = e >> 7, c = e & 127;
        float sum[8];
#pragma unroll
        for (int j = 0; j < 8; ++j) sum[j] = 0.f;
#pragma unroll
        for (int sp = 0; sp < 2; ++sp) {
            const f16x8 v = *(const f16x8*)(Gp + sp * sstride + tb + e);
#pragma unroll
            for (int j = 0; j < 8; ++j) sum[j] += (float)v[j];
        }
        f16x8 o;
#pragma unroll
        for (int j = 0; j < 8; ++j) {
            o[j] = (f16)sum[j];
            tile[r][c + j] = sum[j];
        }
        *(f16x8*)(Gb + (size_t)(ti * 128 + r) * 1024 + tj * 128 + c) = o;
    }
    if (ti != tj) {
        __syncthreads();
#pragma unroll
        for (int i = 0; i < 8; ++i) {
            const int e = (i * 256 + t) * 8;
            const int R = e >> 7, C = e & 127;
            f16x8 o;
#pragma unroll
            for (int j = 0; j < 8; ++j) o[j] = (f16)tile[C + j][R];
            *(f16x8*)(Gb + (size_t)(tj * 128 + R) * 1024 + ti * 128 + C) = o;
        }
    }
}

// ---------------------------------------------------------------------------
// K2 fused: UW2[b] = [Wq^T G_b ; Wv^T G_b]
// ---------------------------------------------------------------------------
__global__ __launch_bounds__(256) void gemm_qv(
    const f16* __restrict__ WqkvT, const f16* __restrict__ G,
    f16* __restrict__ UW2)
{
    __shared__ f16 As[128 * 64];
    __shared__ f16 Bs[128 * 64];
    const int orig = blockIdx.x;
    const int l = (orig & 7) * 128 + (orig >> 3);   // 1024 = 8*128, bijective
    const int bx = l & 7, by = (l >> 3) & 15, b = l >> 7;
    const int tm0 = by * 128, tn0 = bx * 128;
    const int arow = (tm0 < 1024) ? tm0 : tm0 + 1024;   // skip Wk region

    const f16* A  = WqkvT + (size_t)arow * 1024;
    const f16* Bt = G + (size_t)b * (1024 * 1024) + (size_t)tn0 * 1024;

    f32x4 acc[4][4];
#pragma unroll
    for (int i = 0; i < 4; ++i)
#pragma unroll
        for (int j = 0; j < 4; ++j) acc[i][j] = f32x4{0.f, 0.f, 0.f, 0.f};

    gemm_body(A, Bt, 1024, 1024, 1024, As, Bs, acc, threadIdx.x);

    f16* C = UW2 + (size_t)b * (2048 * 1024);
    const int lane = threadIdx.x & 63, w = threadIdx.x >> 6;
    const int wr = w >> 1, wc = w & 1;
    const int cl = lane & 15, rg = lane >> 4;
#pragma unroll
    for (int i = 0; i < 4; ++i)
#pragma unroll
        for (int j = 0; j < 4; ++j) {
            const int cc = tn0 + wc * 64 + j * 16 + cl;
#pragma unroll
            for (int q = 0; q < 4; ++q) {
                const int rr = tm0 + wr * 64 + i * 16 + rg * 4 + q;
                C[(size_t)rr * 1024 + cc] = (f16)acc[i][j][q];
            }
        }
}

// ---------------------------------------------------------------------------
// bias_init: d_out[512][1024] = bias row-broadcast
// ---------------------------------------------------------------------------
__global__ __launch_bounds__(256) void bias_init(
    const float* __restrict__ bias, float* __restrict__ out)
{
    const int idx = blockIdx.x * 1024 + threadIdx.x * 4;
    const float4 bv = *(const float4*)(bias + (idx & 1023));
    *(float4*)(out + idx) = bv;
}

// ---------------------------------------------------------------------------
// K4: d_out += A * Bt^T, split-K=2 via f32 atomics. grid (8,4,2)
// ---------------------------------------------------------------------------
__global__ __launch_bounds__(256) void gemm_out(
    const f16* __restrict__ A, const f16* __restrict__ Bt,
    float* __restrict__ Cout)
{
    __shared__ f16 As[128 * 64];
    __shared__ f16 Bs[128 * 64];
    const int tn0 = blockIdx.x * 128;
    const int tm0 = blockIdx.y * 128;
    const int s = blockIdx.z;
    f32x4 acc[4][4];
#pragma unroll
    for (int i = 0; i < 4; ++i)
#pragma unroll
        for (int j = 0; j < 4; ++j) acc[i][j] = f32x4{0.f, 0.f, 0.f, 0.f};

    gemm_body(A + (size_t)tm0 * 1024 + s * 512,
              Bt + (size_t)tn0 * 1024 + s * 512, 1024, 1024, 512,
              As, Bs, acc, threadIdx.x);

    const int lane = threadIdx.x & 63, w = threadIdx.x >> 6;
    const int wr = w >> 1, wc = w & 1;
    const int cl = lane & 15, rg = lane >> 4;
#pragma unroll
    for (int i = 0; i < 4; ++i)
#pragma unroll
        for (int j = 0; j < 4; ++j) {
            const int cc = tn0 + wc * 64 + j * 16 + cl;
#pragma unroll
            for (int q = 0; q < 4; ++q) {
                const int rr = tm0 + wr * 64 + i * 16 + rg * 4 + q;
                atomicAdd(&Cout[(size_t)rr * 1024 + cc], acc[i][j][q]);
            }
        }
}

// ---------------------------------------------------------------------------
// Per (b,h): dots = U_h * Wk_h^T, vv = W2_h * Wv2_h^T  (64x64, K=1024),
// softmax(dots*0.125), out = attn @ vv -> O (f16)
// grid: (16 heads, 8 batches), block 512 (8 waves)
// wave w: matrix = w>>2 (0 dots, 1 vv), K-quarter = w&3
// ---------------------------------------------------------------------------
__global__ __launch_bounds__(512) void attn_small(
    const f16* __restrict__ UW2, const f16* __restrict__ WqkvT,
    f16* __restrict__ O)
{
    __shared__ float dots[64][66];
    __shared__ float vv[64][66];
    const int h = blockIdx.x, b = blockIdx.y;
    const int tid = threadIdx.x, lane = tid & 63, w = tid >> 6;
    const int isVV = w >> 2;
    const int kq = w & 3;

    const f16* Arows = UW2 + (size_t)b * (2048 * 1024)
                           + (size_t)isVV * (1024 * 1024) + (size_t)h * 64 * 1024;
    const f16* Brows = WqkvT + (size_t)(isVV ? 3072 : 1024) * 1024 + (size_t)h * 64 * 1024;

    f32x4 acc[4][4];
#pragma unroll
    for (int i = 0; i < 4; ++i)
#pragma unroll
        for (int j = 0; j < 4; ++j) acc[i][j] = f32x4{0.f, 0.f, 0.f, 0.f};

    const int cl = lane & 15, kg = lane >> 4;
    for (int ks = 0; ks < 8; ++ks) {
        const int k0 = kq * 256 + ks * 32 + kg * 8;
        f16x8 af[4], bfr[4];
#pragma unroll
        for (int i = 0; i < 4; ++i)
            af[i] = *(const f16x8*)(Arows + (size_t)(i * 16 + cl) * 1024 + k0);
#pragma unroll
        for (int j = 0; j < 4; ++j)
            bfr[j] = *(const f16x8*)(Brows + (size_t)(j * 16 + cl) * 1024 + k0);
#pragma unroll
        for (int i = 0; i < 4; ++i)
#pragma unroll
            for (int j = 0; j < 4; ++j)
                acc[i][j] = __builtin_amdgcn_mfma_f32_16x16x32_f16(af[i], bfr[j], acc[i][j], 0, 0, 0);
    }

    // accumulate K-quarter partials into LDS in 4 barrier rounds
    float (*dst)[66] = isVV ? vv : dots;
#pragma unroll
    for (int r = 0; r < 4; ++r) {
        if (kq == r) {
            if (r == 0) {
#pragma unroll
                for (int i = 0; i < 4; ++i)
#pragma unroll
                    for (int j = 0; j < 4; ++j)
#pragma unroll
                        for (int q = 0; q < 4; ++q)
                            dst[i * 16 + kg * 4 + q][j * 16 + cl] = acc[i][j][q];
            } else {
#pragma unroll
                for (int i = 0; i < 4; ++i)
#pragma unroll
                    for (int j = 0; j < 4; ++j)
#pragma unroll
                        for (int q = 0; q < 4; ++q)
                            dst[i * 16 + kg * 4 + q][j * 16 + cl] += acc[i][j][q];
            }
        }
        __syncthreads();
    }

    // row softmax on dots (scale 0.125)
    if (tid < 64) {
        const int r = tid;
        float mx = -1e30f;
        for (int e = 0; e < 64; ++e) {
            const float v = dots[r][e] * 0.125f;
            dots[r][e] = v;
            mx = fmaxf(mx, v);
        }
        float s = 0.f;
        for (int e = 0; e < 64; ++e) {
            const float v = __expf(dots[r][e] - mx);
            dots[r][e] = v;
            s += v;
        }
        const float inv = 1.f / s;
        for (int e = 0; e < 64; ++e) dots[r][e] *= inv;
    }
    __syncthreads();

    // out = attn @ vv; thread: row r = tid>>3, cols f0..f0+7
    {
        const int r = tid >> 3, f0 = (tid & 7) * 8;
        float o[8];
#pragma unroll
        for (int i = 0; i < 8; ++i) o[i] = 0.f;
        for (int e = 0; e < 64; ++e) {
            const float a = dots[r][e];
#pragma unroll
            for (int i = 0; i < 8; ++i) o[i] += a * vv[e][f0 + i];
        }
        f16* Od = O + (size_t)b * 64 * 1024 + (size_t)r * 1024 + h * 64 + f0;
#pragma unroll
        for (int i = 0; i < 8; ++i) Od[i] = (f16)o[i];
    }
}

// ---------------------------------------------------------------------------
extern "C" void kernel_launch(void* const* d_in, const int* in_sizes, int n_in,
                              void* d_out, int out_size, void* d_ws, size_t ws_size,
                              hipStream_t stream)
{
    const float* x    = (const float*)d_in[0];  // [8][4096][1024]
    const float* Wqkv = (const float*)d_in[1];  // [1024][4096]
    const float* Wout = (const float*)d_in[2];  // [1024][1024]
    const float* bout = (const float*)d_in[3];  // [1024]

    char* ws = (char*)d_ws;
    f16* xT    = (f16*)(ws + 0);           // [8][1024][4096]   67108864 B
    f16* WqkvT = (f16*)(ws + 67108864);    // [4096][1024]       8388608 B
    f16* WoutT = (f16*)(ws + 75497472);    // [1024][1024]       2097152 B
    f16* G     = (f16*)(ws + 77594624);    // [8][1024][1024]   16777216 B
    f16* Gp    = (f16*)(ws + 94371840);    // [2][8][36][16384] 18874368 B (union w/ UW2)
    f16* UW2   = (f16*)(ws + 94371840);    // [8][2048][1024]   33554432 B
    f16* O     = (f16*)(ws + 132120576);   // [8][64][1024]      1048576 B

    tr_cvt_kernel<<<dim3(16, 64, 8), 256, 0, stream>>>(x, xT, 4096, 1024);
    tr_cvt_kernel<<<dim3(64, 16, 1), 256, 0, stream>>>(Wqkv, WqkvT, 1024, 4096);
    tr_cvt_kernel<<<dim3(16, 16, 1), 256, 0, stream>>>(Wout, WoutT, 1024, 1024);

    // K1: symmetric split-K=2 upper tiles -> Gp
    gemm_syk<<<576, 256, 0, stream>>>(xT, Gp);
    // reduce partials + mirror -> G
    reduce_mirror<<<dim3(36, 8), 256, 0, stream>>>(Gp, G);
    // K2 fused: UW2 = [Wq^T G ; Wv^T G]
    gemm_qv<<<1024, 256, 0, stream>>>(WqkvT, G, UW2);
    // K3: per (b,h) small attention
    attn_small<<<dim3(16, 8), 512, 0, stream>>>(UW2, WqkvT, O);
    // K4: out = bias ; out += O @ WoutT^T (split-K=2, f32 atomics)
    bias_init<<<512, 256, 0, stream>>>(bout, (float*)d_out);
    gemm_out<<<dim3(8, 4, 2), 256, 0, stream>>>(O, WoutT, (float*)d_out);
}

// Round 5
// 194.234 us; speedup vs baseline: 1.1942x; 1.1942x over previous
//
#include <hip/hip_runtime.h>
#include <hip/hip_bf16.h>
#include <stdint.h>

typedef _Float16 f16;
typedef _Float16 f16x8 __attribute__((ext_vector_type(8)));
typedef float f32x4 __attribute__((ext_vector_type(4)));

#define AS1 __attribute__((address_space(1)))
#define AS3 __attribute__((address_space(3)))

// ---------------------------------------------------------------------------
// Transpose + fp32->fp16 convert:  src [R][C] f32  ->  dst [C][R] f16
// ---------------------------------------------------------------------------
__global__ __launch_bounds__(256) void tr_cvt_kernel(
    const float* __restrict__ src, f16* __restrict__ dst, int R, int C)
{
    __shared__ float tile[64][65];
    const int b = blockIdx.z;
    src += (size_t)b * R * C;
    dst += (size_t)b * R * C;
    const int c0 = blockIdx.x * 64;
    const int r0 = blockIdx.y * 64;
    const int t = threadIdx.x;
    {
        const int cc = (t & 15) * 4;
        const int rr = t >> 4;
#pragma unroll
        for (int p = 0; p < 4; ++p) {
            const int r = rr + p * 16;
            const float4 v = *(const float4*)(src + (size_t)(r0 + r) * C + c0 + cc);
            tile[r][cc + 0] = v.x; tile[r][cc + 1] = v.y;
            tile[r][cc + 2] = v.z; tile[r][cc + 3] = v.w;
        }
    }
    __syncthreads();
    {
        const int rq = (t & 15) * 4;
        const int cp = t >> 4;
#pragma unroll
        for (int p = 0; p < 4; ++p) {
            const int c = cp + p * 16;
            ushort4 o;
            f16 h0 = (f16)tile[rq + 0][c];
            f16 h1 = (f16)tile[rq + 1][c];
            f16 h2 = (f16)tile[rq + 2][c];
            f16 h3 = (f16)tile[rq + 3][c];
            o.x = __builtin_bit_cast(unsigned short, h0);
            o.y = __builtin_bit_cast(unsigned short, h1);
            o.z = __builtin_bit_cast(unsigned short, h2);
            o.w = __builtin_bit_cast(unsigned short, h3);
            *(ushort4*)(dst + (size_t)(c0 + c) * R + r0 + rq) = o;
        }
    }
}

// ---------------------------------------------------------------------------
// 256x256-tile, BK=64, 512-thread (8-wave, 2x4) GEMM core.
// Double-buffered LDS (2x32KB per matrix), global_load_lds-16B staging of
// step t+1 issued BEFORE computing step t, counted vmcnt(8), raw barriers.
// LDS layout: [row][64] f16 with 16B-chunk XOR swizzle (chunk ^= row&7);
// gload_lds writes linearly -> global SOURCE chunk is inverse-swizzled
// (rule 21), reads apply the same XOR. 2-way bank aliasing only.
// ---------------------------------------------------------------------------
__device__ __forceinline__ void stage256(
    const f16* __restrict__ src, int ld, char* ldsbase, int tid)
{
    const int lane = tid & 63;
    const int gch = ((lane & 7) ^ (lane >> 3)) * 8;   // inverse-swizzled source
    const int rowl = tid >> 3;                        // 0..63 (w*8 + lane>>3)
    const int wbase = (tid >> 3) & ~7;                // wave-uniform: w*8
#pragma unroll
    for (int p = 0; p < 4; ++p) {
        const f16* s = src + (size_t)(p * 64 + rowl) * ld + gch;
        __builtin_amdgcn_global_load_lds(
            (const AS1 uint32_t*)s,
            (AS3 uint32_t*)(ldsbase + (p * 64 + wbase) * 128), 16, 0, 0);
    }
}

__device__ __forceinline__ void gemm256_core(
    const f16* __restrict__ A, const f16* __restrict__ Bt,
    int lda, int ldb, int nsteps,
    f16* As, f16* Bs, f32x4 (&acc)[8][4], int tid)
{
    const int lane = tid & 63, w = tid >> 6;
    const int wr = w >> 2, wc = w & 3;
    const int cl = lane & 15, kg = lane >> 4, b7 = lane & 7;

    // prologue: stage step 0 into buffer 0
    stage256(A, lda, (char*)As, tid);
    stage256(Bt, ldb, (char*)Bs, tid);

    for (int t = 0; t < nsteps; ++t) {
        const int cur = t & 1;
        if (t + 1 < nsteps) {
            const int k0 = (t + 1) * 64;
            stage256(A + k0, lda, (char*)As + (cur ^ 1) * 32768, tid);
            stage256(Bt + k0, ldb, (char*)Bs + (cur ^ 1) * 32768, tid);
            asm volatile("s_waitcnt vmcnt(8)" ::: "memory");  // step t's 8 loads done
        } else {
            asm volatile("s_waitcnt vmcnt(0)" ::: "memory");
        }
        __builtin_amdgcn_s_barrier();   // buf[cur] complete for all waves
        const f16* Ab = As + cur * 16384;
        const f16* Bb = Bs + cur * 16384;
#pragma unroll
        for (int kk = 0; kk < 2; ++kk) {
            const int ch = (kk * 4 + kg) ^ b7;   // swizzled 16B chunk
            f16x8 af[8], bf[4];
#pragma unroll
            for (int i = 0; i < 8; ++i)
                af[i] = *(const f16x8*)&Ab[(wr * 128 + i * 16 + cl) * 64 + ch * 8];
#pragma unroll
            for (int j = 0; j < 4; ++j)
                bf[j] = *(const f16x8*)&Bb[(wc * 64 + j * 16 + cl) * 64 + ch * 8];
#pragma unroll
            for (int i = 0; i < 8; ++i)
#pragma unroll
                for (int j = 0; j < 4; ++j)
                    acc[i][j] = __builtin_amdgcn_mfma_f32_16x16x32_f16(af[i], bf[j], acc[i][j], 0, 0, 0);
        }
        __builtin_amdgcn_s_barrier();   // all waves done reading buf[cur]
    }
}

// ---------------------------------------------------------------------------
// K1: Gp[s][b] = xT_b[:, s*2048 : +2048] self-product (full G, split-K=2).
// grid: 256 blocks (16 tiles x 8 batch x 2 splits), XCD-chunked swizzle.
// ---------------------------------------------------------------------------
__global__ __launch_bounds__(512) void gemm_syk256(
    const f16* __restrict__ xT, f16* __restrict__ Gp)
{
    __shared__ f16 As[2 * 256 * 64];
    __shared__ f16 Bs[2 * 256 * 64];
    const int orig = blockIdx.x;
    const int l = (orig & 7) * 32 + (orig >> 3);   // 256 = 8*32, bijective
    const int tile = l & 15, b = (l >> 4) & 7, s = l >> 7;
    const int ti = tile >> 2, tj = tile & 3;

    const f16* base = xT + (size_t)b * (1024 * 4096) + (size_t)s * 2048;
    const f16* A  = base + (size_t)ti * 256 * 4096;
    const f16* Bt = base + (size_t)tj * 256 * 4096;

    f32x4 acc[8][4];
#pragma unroll
    for (int i = 0; i < 8; ++i)
#pragma unroll
        for (int j = 0; j < 4; ++j) acc[i][j] = f32x4{0.f, 0.f, 0.f, 0.f};

    gemm256_core(A, Bt, 4096, 4096, 32, As, Bs, acc, threadIdx.x);

    f16* out = Gp + ((size_t)s * 8 + b) * 1048576;
    const int lane = threadIdx.x & 63, w = threadIdx.x >> 6;
    const int wr = w >> 2, wc = w & 3;
    const int cl = lane & 15, rg = lane >> 4;
#pragma unroll
    for (int i = 0; i < 8; ++i)
#pragma unroll
        for (int j = 0; j < 4; ++j)
#pragma unroll
            for (int q = 0; q < 4; ++q) {
                const int row = ti * 256 + wr * 128 + i * 16 + rg * 4 + q;
                const int col = tj * 256 + wc * 64 + j * 16 + cl;
                out[(size_t)row * 1024 + col] = (f16)acc[i][j][q];
            }
}

// ---------------------------------------------------------------------------
// reduce: G = Gp[0] + Gp[1]  (elementwise, f32 accumulate)
// ---------------------------------------------------------------------------
__global__ __launch_bounds__(256) void reduce_sum(
    const f16* __restrict__ Gp, f16* __restrict__ G)
{
    const size_t i = ((size_t)blockIdx.x * 256 + threadIdx.x) * 8;
    const f16x8 a = *(const f16x8*)(Gp + i);
    const f16x8 c = *(const f16x8*)(Gp + 8388608 + i);
    f16x8 o;
#pragma unroll
    for (int j = 0; j < 8; ++j) o[j] = (f16)((float)a[j] + (float)c[j]);
    *(f16x8*)(G + i) = o;
}

// ---------------------------------------------------------------------------
// K2 fused (256^2): UW2[b] = [Wq^T G_b ; Wv^T G_b]
// grid: 256 blocks (4 N x 8 M x 8 batch), XCD-chunked swizzle. K=1024.
// ---------------------------------------------------------------------------
__global__ __launch_bounds__(512) void gemm_qv256(
    const f16* __restrict__ WqkvT, const f16* __restrict__ G,
    f16* __restrict__ UW2)
{
    __shared__ f16 As[2 * 256 * 64];
    __shared__ f16 Bs[2 * 256 * 64];
    const int orig = blockIdx.x;
    const int l = (orig & 7) * 32 + (orig >> 3);
    const int bx = l & 3, by = (l >> 2) & 7, b = l >> 5;
    const int arow = (by < 4) ? by * 256 : 2048 + (by - 4) * 256;  // skip Wk

    const f16* A  = WqkvT + (size_t)arow * 1024;
    const f16* Bt = G + (size_t)b * 1048576 + (size_t)bx * 256 * 1024;

    f32x4 acc[8][4];
#pragma unroll
    for (int i = 0; i < 8; ++i)
#pragma unroll
        for (int j = 0; j < 4; ++j) acc[i][j] = f32x4{0.f, 0.f, 0.f, 0.f};

    gemm256_core(A, Bt, 1024, 1024, 16, As, Bs, acc, threadIdx.x);

    f16* C = UW2 + (size_t)b * 2097152;
    const int lane = threadIdx.x & 63, w = threadIdx.x >> 6;
    const int wr = w >> 2, wc = w & 3;
    const int cl = lane & 15, rg = lane >> 4;
#pragma unroll
    for (int i = 0; i < 8; ++i)
#pragma unroll
        for (int j = 0; j < 4; ++j) {
            const int cc = bx * 256 + wc * 64 + j * 16 + cl;
#pragma unroll
            for (int q = 0; q < 4; ++q) {
                const int rr = by * 256 + wr * 128 + i * 16 + rg * 4 + q;
                C[(size_t)rr * 1024 + cc] = (f16)acc[i][j][q];
            }
        }
}

// ---------------------------------------------------------------------------
// Legacy 128x128 body (used by gemm_out only)
// ---------------------------------------------------------------------------
__device__ __forceinline__ void gemm_body(
    const f16* __restrict__ A, const f16* __restrict__ Bt,
    int lda, int ldb, int K, f16* As, f16* Bs,
    f32x4 (&acc)[4][4], int tid)
{
    const int lane = tid & 63, w = tid >> 6;
    const int wr = w >> 1, wc = w & 1;
    const int lrow = lane >> 3;
    const int lcol = (lane & 7) * 8;
    for (int k0 = 0; k0 < K; k0 += 64) {
#pragma unroll
        for (int p = 0; p < 4; ++p) {
            const f16* sa = A + (size_t)(p * 32 + w * 8 + lrow) * lda + k0 + lcol;
            __builtin_amdgcn_global_load_lds(
                (const AS1 uint32_t*)sa,
                (AS3 uint32_t*)((char*)As + p * 4096 + w * 1024), 16, 0, 0);
            const f16* sb = Bt + (size_t)(p * 32 + w * 8 + lrow) * ldb + k0 + lcol;
            __builtin_amdgcn_global_load_lds(
                (const AS1 uint32_t*)sb,
                (AS3 uint32_t*)((char*)Bs + p * 4096 + w * 1024), 16, 0, 0);
        }
        __syncthreads();
#pragma unroll
        for (int kk = 0; kk < 2; ++kk) {
            f16x8 af[4], bfr[4];
#pragma unroll
            for (int i = 0; i < 4; ++i)
                af[i] = *(const f16x8*)&As[(wr * 64 + i * 16 + (lane & 15)) * 64 + kk * 32 + (lane >> 4) * 8];
#pragma unroll
            for (int j = 0; j < 4; ++j)
                bfr[j] = *(const f16x8*)&Bs[(wc * 64 + j * 16 + (lane & 15)) * 64 + kk * 32 + (lane >> 4) * 8];
#pragma unroll
            for (int i = 0; i < 4; ++i)
#pragma unroll
                for (int j = 0; j < 4; ++j)
                    acc[i][j] = __builtin_amdgcn_mfma_f32_16x16x32_f16(af[i], bfr[j], acc[i][j], 0, 0, 0);
        }
        __syncthreads();
    }
}

// ---------------------------------------------------------------------------
// bias_init: d_out[512][1024] = bias row-broadcast
// ---------------------------------------------------------------------------
__global__ __launch_bounds__(256) void bias_init(
    const float* __restrict__ bias, float* __restrict__ out)
{
    const int idx = blockIdx.x * 1024 + threadIdx.x * 4;
    const float4 bv = *(const float4*)(bias + (idx & 1023));
    *(float4*)(out + idx) = bv;
}

// ---------------------------------------------------------------------------
// K4: d_out += A * Bt^T, split-K=2 via f32 atomics. grid (8,4,2)
// ---------------------------------------------------------------------------
__global__ __launch_bounds__(256) void gemm_out(
    const f16* __restrict__ A, const f16* __restrict__ Bt,
    float* __restrict__ Cout)
{
    __shared__ f16 As[128 * 64];
    __shared__ f16 Bs[128 * 64];
    const int tn0 = blockIdx.x * 128;
    const int tm0 = blockIdx.y * 128;
    const int s = blockIdx.z;
    f32x4 acc[4][4];
#pragma unroll
    for (int i = 0; i < 4; ++i)
#pragma unroll
        for (int j = 0; j < 4; ++j) acc[i][j] = f32x4{0.f, 0.f, 0.f, 0.f};

    gemm_body(A + (size_t)tm0 * 1024 + s * 512,
              Bt + (size_t)tn0 * 1024 + s * 512, 1024, 1024, 512,
              As, Bs, acc, threadIdx.x);

    const int lane = threadIdx.x & 63, w = threadIdx.x >> 6;
    const int wr = w >> 1, wc = w & 1;
    const int cl = lane & 15, rg = lane >> 4;
#pragma unroll
    for (int i = 0; i < 4; ++i)
#pragma unroll
        for (int j = 0; j < 4; ++j) {
            const int cc = tn0 + wc * 64 + j * 16 + cl;
#pragma unroll
            for (int q = 0; q < 4; ++q) {
                const int rr = tm0 + wr * 64 + i * 16 + rg * 4 + q;
                atomicAdd(&Cout[(size_t)rr * 1024 + cc], acc[i][j][q]);
            }
        }
}

// ---------------------------------------------------------------------------
// Per (b,h): dots = U_h * Wk_h^T, vv = W2_h * Wv2_h^T  (64x64, K=1024),
// softmax(dots*0.125), out = attn @ vv -> O (f16)
// grid: (16 heads, 8 batches), block 512 (8 waves)
// ---------------------------------------------------------------------------
__global__ __launch_bounds__(512) void attn_small(
    const f16* __restrict__ UW2, const f16* __restrict__ WqkvT,
    f16* __restrict__ O)
{
    __shared__ float dots[64][66];
    __shared__ float vv[64][66];
    const int h = blockIdx.x, b = blockIdx.y;
    const int tid = threadIdx.x, lane = tid & 63, w = tid >> 6;
    const int isVV = w >> 2;
    const int kq = w & 3;

    const f16* Arows = UW2 + (size_t)b * (2048 * 1024)
                           + (size_t)isVV * (1024 * 1024) + (size_t)h * 64 * 1024;
    const f16* Brows = WqkvT + (size_t)(isVV ? 3072 : 1024) * 1024 + (size_t)h * 64 * 1024;

    f32x4 acc[4][4];
#pragma unroll
    for (int i = 0; i < 4; ++i)
#pragma unroll
        for (int j = 0; j < 4; ++j) acc[i][j] = f32x4{0.f, 0.f, 0.f, 0.f};

    const int cl = lane & 15, kg = lane >> 4;
    for (int ks = 0; ks < 8; ++ks) {
        const int k0 = kq * 256 + ks * 32 + kg * 8;
        f16x8 af[4], bfr[4];
#pragma unroll
        for (int i = 0; i < 4; ++i)
            af[i] = *(const f16x8*)(Arows + (size_t)(i * 16 + cl) * 1024 + k0);
#pragma unroll
        for (int j = 0; j < 4; ++j)
            bfr[j] = *(const f16x8*)(Brows + (size_t)(j * 16 + cl) * 1024 + k0);
#pragma unroll
        for (int i = 0; i < 4; ++i)
#pragma unroll
            for (int j = 0; j < 4; ++j)
                acc[i][j] = __builtin_amdgcn_mfma_f32_16x16x32_f16(af[i], bfr[j], acc[i][j], 0, 0, 0);
    }

    float (*dst)[66] = isVV ? vv : dots;
#pragma unroll
    for (int r = 0; r < 4; ++r) {
        if (kq == r) {
            if (r == 0) {
#pragma unroll
                for (int i = 0; i < 4; ++i)
#pragma unroll
                    for (int j = 0; j < 4; ++j)
#pragma unroll
                        for (int q = 0; q < 4; ++q)
                            dst[i * 16 + kg * 4 + q][j * 16 + cl] = acc[i][j][q];
            } else {
#pragma unroll
                for (int i = 0; i < 4; ++i)
#pragma unroll
                    for (int j = 0; j < 4; ++j)
#pragma unroll
                        for (int q = 0; q < 4; ++q)
                            dst[i * 16 + kg * 4 + q][j * 16 + cl] += acc[i][j][q];
            }
        }
        __syncthreads();
    }

    if (tid < 64) {
        const int r = tid;
        float mx = -1e30f;
        for (int e = 0; e < 64; ++e) {
            const float v = dots[r][e] * 0.125f;
            dots[r][e] = v;
            mx = fmaxf(mx, v);
        }
        float s = 0.f;
        for (int e = 0; e < 64; ++e) {
            const float v = __expf(dots[r][e] - mx);
            dots[r][e] = v;
            s += v;
        }
        const float inv = 1.f / s;
        for (int e = 0; e < 64; ++e) dots[r][e] *= inv;
    }
    __syncthreads();

    {
        const int r = tid >> 3, f0 = (tid & 7) * 8;
        float o[8];
#pragma unroll
        for (int i = 0; i < 8; ++i) o[i] = 0.f;
        for (int e = 0; e < 64; ++e) {
            const float a = dots[r][e];
#pragma unroll
            for (int i = 0; i < 8; ++i) o[i] += a * vv[e][f0 + i];
        }
        f16* Od = O + (size_t)b * 64 * 1024 + (size_t)r * 1024 + h * 64 + f0;
#pragma unroll
        for (int i = 0; i < 8; ++i) Od[i] = (f16)o[i];
    }
}

// ---------------------------------------------------------------------------
extern "C" void kernel_launch(void* const* d_in, const int* in_sizes, int n_in,
                              void* d_out, int out_size, void* d_ws, size_t ws_size,
                              hipStream_t stream)
{
    const float* x    = (const float*)d_in[0];  // [8][4096][1024]
    const float* Wqkv = (const float*)d_in[1];  // [1024][4096]
    const float* Wout = (const float*)d_in[2];  // [1024][1024]
    const float* bout = (const float*)d_in[3];  // [1024]

    char* ws = (char*)d_ws;
    f16* xT    = (f16*)(ws + 0);           // [8][1024][4096]   67108864 B
    f16* WqkvT = (f16*)(ws + 67108864);    // [4096][1024]       8388608 B
    f16* WoutT = (f16*)(ws + 75497472);    // [1024][1024]       2097152 B
    f16* G     = (f16*)(ws + 77594624);    // [8][1024][1024]   16777216 B
    f16* Gp    = (f16*)(ws + 94371840);    // [2][8][1024][1024] 33554432 B
    f16* UW2   = (f16*)(ws + 94371840);    // union w/ Gp (qv runs after reduce)
    f16* O     = (f16*)(ws + 127926272);   // [8][64][1024]      1048576 B

    tr_cvt_kernel<<<dim3(16, 64, 8), 256, 0, stream>>>(x, xT, 4096, 1024);
    tr_cvt_kernel<<<dim3(64, 16, 1), 256, 0, stream>>>(Wqkv, WqkvT, 1024, 4096);
    tr_cvt_kernel<<<dim3(16, 16, 1), 256, 0, stream>>>(Wout, WoutT, 1024, 1024);

    // K1: full-G split-K=2, 256^2 tiles, pipelined
    gemm_syk256<<<256, 512, 0, stream>>>(xT, Gp);
    // G = Gp0 + Gp1
    reduce_sum<<<4096, 256, 0, stream>>>(Gp, G);
    // K2 fused: UW2 = [Wq^T G ; Wv^T G], 256^2 tiles, pipelined
    gemm_qv256<<<256, 512, 0, stream>>>(WqkvT, G, UW2);
    // K3: per (b,h) small attention
    attn_small<<<dim3(16, 8), 512, 0, stream>>>(UW2, WqkvT, O);
    // K4: out = bias ; out += O @ WoutT^T (split-K=2, f32 atomics)
    bias_init<<<512, 256, 0, stream>>>(bout, (float*)d_out);
    gemm_out<<<dim3(8, 4, 2), 256, 0, stream>>>(O, WoutT, (float*)d_out);
}